// Round 8
// baseline (385.582 us; speedup 1.0000x reference)
//
#include <hip/hip_runtime.h>
#include <hip/hip_bf16.h>

#define BATCH 8
#define NPTS  131072
#define DIM   32
#define NLAB  33
#define B1    256   // pass1 blocks per batch (512 points/block, 4 steps/wave)
#define B2    512   // pass2 blocks per batch

// ws layout (floats unless noted)
#define OFF_PART  0                         // 2048 * 1056 partial sums
#define OFF_PCNT  (2048 * 1056)             // 2048 * 33 ints
#define OFF_SUM   (OFF_PCNT + 2048 * 33)    // 8448
#define OFF_CNT   (OFF_SUM + 8448)          // 264
#define OFF_PULL  (OFF_CNT + 264)           // 8
#define OFF_CTR   (OFF_PULL + 8)            // 1 uint

typedef short  bf16x8 __attribute__((ext_vector_type(8)));
typedef float  f32x4  __attribute__((ext_vector_type(4)));

static __device__ __forceinline__ short f2bf(float f) {
  __hip_bfloat16 h = __float2bfloat16(f);
  return *reinterpret_cast<short*>(&h);
}

// Pass 1: sums[l][d] = onehot(labels)^T @ E via MFMA, one-hot A from direct
// label loads, B-fragments loaded straight from global in MFMA layout.
// No LDS, no barriers, no atomics in the hot loop. Per-block partial output
// (fully written -> no pre-zeroing memset dispatch needed).
__global__ __launch_bounds__(256, 6) void pass1_kernel(
    const float* __restrict__ emb, const int* __restrict__ lab,
    float* __restrict__ part, int* __restrict__ pcnt) {
  const int b    = blockIdx.y;
  const int bx   = blockIdx.x;
  const int tid  = threadIdx.x;
  const int w    = tid >> 6;
  const int lane = tid & 63;
  const int m0   = lane & 15;   // A row (label in tile) / B col (dim)
  const int g    = lane >> 4;   // k-group

  __shared__ float s_stage[4][NLAB * DIM];   // 16.9 KB (epilogue only)
  __shared__ int   s_cnt[4][NLAB];

  f32x4 acc[3][2];
#pragma unroll
  for (int t = 0; t < 3; ++t)
#pragma unroll
    for (int u = 0; u < 2; ++u) acc[t][u] = (f32x4){0.f, 0.f, 0.f, 0.f};
  int cnt0 = 0, cnt1 = 0, cnt2 = 0;

  const size_t bbase = (size_t)b * NPTS + (size_t)bx * 512 + w * 128;

#pragma unroll 2
  for (int s = 0; s < 4; ++s) {
    const size_t pt = bbase + s * 32;
    const float* eb = emb + pt * DIM;

    int lj[8];
#pragma unroll
    for (int j = 0; j < 8; ++j) lj[j] = lab[pt + g * 8 + j];

    bf16x8 a0, a1, a2, b0, b1;
#pragma unroll
    for (int j = 0; j < 8; ++j) {
      b0[j] = f2bf(eb[(g * 8 + j) * DIM + m0]);
      b1[j] = f2bf(eb[(g * 8 + j) * DIM + m0 + 16]);
      const int h0 = (lj[j] == m0), h1 = (lj[j] == m0 + 16), h2 = (lj[j] == m0 + 32);
      a0[j] = h0 ? (short)0x3F80 : (short)0;
      a1[j] = h1 ? (short)0x3F80 : (short)0;
      a2[j] = h2 ? (short)0x3F80 : (short)0;
      cnt0 += h0; cnt1 += h1; cnt2 += h2;
    }

    acc[0][0] = __builtin_amdgcn_mfma_f32_16x16x32_bf16(a0, b0, acc[0][0], 0, 0, 0);
    acc[0][1] = __builtin_amdgcn_mfma_f32_16x16x32_bf16(a0, b1, acc[0][1], 0, 0, 0);
    acc[1][0] = __builtin_amdgcn_mfma_f32_16x16x32_bf16(a1, b0, acc[1][0], 0, 0, 0);
    acc[1][1] = __builtin_amdgcn_mfma_f32_16x16x32_bf16(a1, b1, acc[1][1], 0, 0, 0);
    acc[2][0] = __builtin_amdgcn_mfma_f32_16x16x32_bf16(a2, b0, acc[2][0], 0, 0, 0);
    acc[2][1] = __builtin_amdgcn_mfma_f32_16x16x32_bf16(a2, b1, acc[2][1], 0, 0, 0);
  }

  // counts: reduce across the 4 k-groups
  cnt0 += __shfl_xor(cnt0, 16); cnt0 += __shfl_xor(cnt0, 32);
  cnt1 += __shfl_xor(cnt1, 16); cnt1 += __shfl_xor(cnt1, 32);
  cnt2 += __shfl_xor(cnt2, 16); cnt2 += __shfl_xor(cnt2, 32);
  if (lane < 16)      s_cnt[w][m0]      = cnt0;
  else if (lane < 32) s_cnt[w][m0 + 16] = cnt1;
  if (lane == 32)     s_cnt[w][32]      = cnt2;

  // dump accumulators as [label][dim]; D layout: row=g*4+r, col=m0(+16u)
  float* st = s_stage[w];
#pragma unroll
  for (int t = 0; t < 2; ++t)
#pragma unroll
    for (int u = 0; u < 2; ++u)
#pragma unroll
      for (int r = 0; r < 4; ++r)
        st[(t * 16 + g * 4 + r) * DIM + m0 + 16 * u] = acc[t][u][r];
  if (lane < 16) {
    st[32 * DIM + m0]      = acc[2][0][0];
    st[32 * DIM + m0 + 16] = acc[2][1][0];
  }
  __syncthreads();

  // cross-wave reduce -> per-block partial (coalesced, fully written)
  const int blk = b * B1 + bx;
  for (int i = tid; i < NLAB * DIM; i += 256)
    part[(size_t)blk * (NLAB * DIM) + i] =
        s_stage[0][i] + s_stage[1][i] + s_stage[2][i] + s_stage[3][i];
  if (tid < NLAB)
    pcnt[blk * NLAB + tid] =
        s_cnt[0][tid] + s_cnt[1][tid] + s_cnt[2][tid] + s_cnt[3][tid];
}

// Reduce partials -> gsum/gcnt; init pullb and the pass2 done-counter.
// R7 bug: housekeeping used thread ids 264..272 in a 256-thread block ->
// ctr stayed poisoned, finish phase never ran. All indices now < 256.
__global__ __launch_bounds__(256) void reduce_kernel(
    const float* __restrict__ part, const int* __restrict__ pcnt,
    float* __restrict__ gsum, float* __restrict__ gcnt,
    float* __restrict__ pullb, unsigned* __restrict__ ctr) {
  const int o = blockIdx.x * 256 + threadIdx.x;   // 0..8447 (33 blocks)
  {
    const int b = o / (NLAB * DIM), r = o % (NLAB * DIM);
    float s = 0.f;
    const float* p = part + (size_t)(b * B1) * (NLAB * DIM) + r;
#pragma unroll 8
    for (int k = 0; k < B1; ++k) s += p[(size_t)k * (NLAB * DIM)];
    gsum[o] = s;
  }

  if (blockIdx.x == 0) {
    const int tid = threadIdx.x;
    for (int t = tid; t < BATCH * NLAB; t += 256) {   // 264 items, strided
      const int bb = t / NLAB, l = t % NLAB;
      int c = 0;
      const int* q = pcnt + bb * B1 * NLAB + l;
#pragma unroll 8
      for (int k = 0; k < B1; ++k) c += q[k * NLAB];
      gcnt[t] = (float)c;
    }
    if (tid < BATCH) pullb[tid] = 0.f;
    if (tid == BATCH) *ctr = 0u;
  }
}

// Pass 2: per-point hinge (weight-folded) + last-block-done finish phase
// (push + combine) via device-scope counter — no separate finish dispatch.
__global__ __launch_bounds__(256) void pass2_kernel(
    const float* __restrict__ emb, const int* __restrict__ lab,
    const float* __restrict__ gsum, const float* __restrict__ gcnt,
    float* __restrict__ pullb, unsigned* __restrict__ ctr,
    float* __restrict__ out) {
  const int b   = blockIdx.y;
  const int tid = threadIdx.x;
  __shared__ __align__(16) float s_mean[NLAB * 36];
  __shared__ float s_w[NLAB];
  __shared__ float s_red[4];
  __shared__ __align__(16) float s_mn[32 * DIM];   // finish: normalized means
  __shared__ int   s_pres[32];
  __shared__ float s_hp[4], s_pm[4], s_ps[BATCH];
  __shared__ int   s_islast;

  for (int i = tid; i < NLAB * DIM; i += 256) {
    const int l = i >> 5, d = i & 31;
    const float c = gcnt[b * NLAB + l];
    s_mean[l * 36 + d] = gsum[b * (NLAB * DIM) + i] / fmaxf(c, 1.0f);
  }
  if (tid < 64) {
    const float c = (tid < NLAB) ? gcnt[b * NLAB + tid] : 0.f;
    const int pres = (tid >= 1 && tid < NLAB && c > 0.f) ? 1 : 0;
    const unsigned long long bal = __ballot(pres);
    const float n_inst = (float)__popcll(bal);
    if (tid < NLAB)
      s_w[tid] = pres ? 1.f / (fmaxf(c, 1.f) * (n_inst + 1e-6f)) : 0.f;
  }
  __syncthreads();

  const int sub   = tid >> 3;
  const int lane8 = tid & 7;
  const int d0    = lane8 << 2;
  const size_t base = (size_t)b * NPTS;
  const int p0 = blockIdx.x * 32 + sub;
  constexpr int NIT = NPTS / (B2 * 32);   // 8

  int labs[NIT];
#pragma unroll
  for (int it = 0; it < NIT; ++it)
    labs[it] = lab[base + p0 + it * (B2 * 32)];

  float wacc = 0.f;
#pragma unroll
  for (int it = 0; it < NIT; ++it) {
    const int p = p0 + it * (B2 * 32);
    const int l = labs[it];
    const float4 e = *(const float4*)(emb + (base + p) * DIM + d0);
    const float4 m = *(const float4*)(s_mean + l * 36 + d0);
    const float dx = e.x - m.x, dy = e.y - m.y, dz = e.z - m.z, dw = e.w - m.w;
    float s = dx * dx + dy * dy + dz * dz + dw * dw;
    s += __shfl_xor(s, 1);
    s += __shfl_xor(s, 2);
    s += __shfl_xor(s, 4);
    if (lane8 == 0) {
      const float dist = sqrtf(s + 1e-24f);
      wacc += s_w[l] * fmaxf(dist - 0.1f, 0.f);
    }
  }
#pragma unroll
  for (int m = 1; m < 64; m <<= 1) wacc += __shfl_xor(wacc, m);
  if ((tid & 63) == 0) s_red[tid >> 6] = wacc;
  __syncthreads();
  if (tid == 0) {
    atomicAdd(&pullb[b], s_red[0] + s_red[1] + s_red[2] + s_red[3]);
    __threadfence();
    const unsigned v = atomicAdd(ctr, 1u);
    s_islast = (v == (unsigned)(B2 * BATCH - 1)) ? 1 : 0;
  }
  __syncthreads();
  if (!s_islast) return;

  // ---- finish phase (exactly one block reaches here, after all others) ----
  __threadfence();
  const int fl  = tid >> 3;        // label-1 index 0..31
  const int fs  = tid & 7;         // dim quad 0..7

  for (int bb = 0; bb < BATCH; ++bb) {
    // normalized mean for label fl+1 (8 lanes per label, contiguous in wave)
    const float cnt = gcnt[bb * NLAB + fl + 1];
    float4 v = *(const float4*)(gsum + (size_t)(bb * NLAB + fl + 1) * DIM + fs * 4);
    const float inv = 1.f / fmaxf(cnt, 1.f);
    v.x *= inv; v.y *= inv; v.z *= inv; v.w *= inv;
    float n2 = v.x * v.x + v.y * v.y + v.z * v.z + v.w * v.w;
    n2 += __shfl_xor(n2, 1);
    n2 += __shfl_xor(n2, 2);
    n2 += __shfl_xor(n2, 4);
    const float scale = 1.f / fmaxf(sqrtf(n2), 1e-12f);
    v.x *= scale; v.y *= scale; v.z *= scale; v.w *= scale;
    *(float4*)(s_mn + fl * DIM + fs * 4) = v;
    if (fs == 0) s_pres[fl] = (cnt > 0.f) ? 1 : 0;
    if (tid < 4) { s_hp[tid] = 0.f; s_pm[tid] = 0.f; }
    __syncthreads();

    float hp = 0.f, pm = 0.f;
    for (int idx = tid; idx < 1024; idx += 256) {
      const int i = idx >> 5, j = idx & 31;
      if (j > i && s_pres[i] && s_pres[j]) {
        const float4* a = (const float4*)(s_mn + i * DIM);
        const float4* c = (const float4*)(s_mn + j * DIM);
        float sq = 0.f;
#pragma unroll
        for (int q = 0; q < 8; ++q) {
          const float4 av = a[q], cv = c[q];
          const float ddx = av.x - cv.x, ddy = av.y - cv.y;
          const float ddz = av.z - cv.z, ddw = av.w - cv.w;
          sq += ddx * ddx + ddy * ddy + ddz * ddz + ddw * ddw;
        }
        const float dmat = sqrtf(sq + 1e-24f);
        hp += fmaxf(1.0f - dmat, 0.f);   // 2*DELTA_D = 1.0
        pm += 1.f;
      }
    }
#pragma unroll
    for (int m = 1; m < 64; m <<= 1) {
      hp += __shfl_xor(hp, m);
      pm += __shfl_xor(pm, m);
    }
    if ((tid & 63) == 0) { s_hp[tid >> 6] = hp; s_pm[tid >> 6] = pm; }
    __syncthreads();
    if (tid == 0) {
      int ni = 0;
      for (int i = 0; i < 32; ++i) ni += s_pres[i];
      const float hpt = s_hp[0] + s_hp[1] + s_hp[2] + s_hp[3];
      const float pmt = s_pm[0] + s_pm[1] + s_pm[2] + s_pm[3];
      s_ps[bb] = (ni > 1) ? hpt / (pmt + 1e-6f) : 0.f;
    }
    __syncthreads();
  }

  if (tid < 64) {
    const int t = tid;
    float pl = 0.f, ps = 0.f;
    if (t < BATCH) {
      pl = atomicAdd(&pullb[t], 0.f);   // device-scope coherent read
      ps = s_ps[t];
    }
#pragma unroll
    for (int m = 1; m < 64; m <<= 1) {
      pl += __shfl_xor(pl, m);
      ps += __shfl_xor(ps, m);
    }
    if (t == 0) {
      const float pull_m = pl / (float)BATCH;
      const float push_m = ps / (float)BATCH;
      out[0] = pull_m + push_m;
      out[1] = pull_m;
      out[2] = push_m;
    }
  }
}

extern "C" void kernel_launch(void* const* d_in, const int* in_sizes, int n_in,
                              void* d_out, int out_size, void* d_ws, size_t ws_size,
                              hipStream_t stream) {
  const float* emb = (const float*)d_in[0];
  const int*   lab = (const int*)d_in[1];
  float* out = (float*)d_out;
  float* ws  = (float*)d_ws;

  float*    part  = ws + OFF_PART;
  int*      pcnt  = (int*)(ws + OFF_PCNT);
  float*    gsum  = ws + OFF_SUM;
  float*    gcnt  = ws + OFF_CNT;
  float*    pullb = ws + OFF_PULL;
  unsigned* ctr   = (unsigned*)(ws + OFF_CTR);

  pass1_kernel<<<dim3(B1, BATCH), 256, 0, stream>>>(emb, lab, part, pcnt);
  reduce_kernel<<<33, 256, 0, stream>>>(part, pcnt, gsum, gcnt, pullb, ctr);
  pass2_kernel<<<dim3(B2, BATCH), 256, 0, stream>>>(emb, lab, gsum, gcnt,
                                                    pullb, ctr, out);
}